// Round 1
// baseline (182.977 us; speedup 1.0000x reference)
//
#include <hip/hip_runtime.h>
#include <hip/hip_bf16.h>

// Problem constants (fixed by setup_inputs): Na=Nb=200000, Da=Db=64, S=256.
#define NKEYS   (1 << 24)        // 256^3 possible locations
#define NBLK    16384            // NKEYS / 1024
#define MAXN    400000           // Na + Nb

// Device-global scratch (avoids relying on ws_size). Re-initialized every call.
__device__ unsigned int g_counts[NKEYS];      // presence -> then rank, per key
__device__ unsigned int g_blockSums[NBLK];    // per-1024-key block count -> exclusive base
__device__ int          g_winner_a[MAXN];     // per-unique-slot winning a-row (max index)
__device__ int          g_winner_b[MAXN];     // per-unique-slot winning b-row (max index)

// ---------------------------------------------------------------- init
__global__ void k_zero_counts() {
    int i = blockIdx.x * blockDim.x + threadIdx.x;     // NKEYS/4 threads
    reinterpret_cast<uint4*>(g_counts)[i] = make_uint4(0u, 0u, 0u, 0u);
}

__global__ void k_init(float* out_loc, int N) {
    int i = blockIdx.x * blockDim.x + threadIdx.x;     // N*3 threads
    if (i < N) { g_winner_a[i] = -1; g_winner_b[i] = -1; }
    if (i < N * 3) out_loc[i] = -1.0f;                 // fill_value=-1 padding rows
}

// ---------------------------------------------------------------- mark presence
__global__ void k_mark(const int* __restrict__ a_loc, const int* __restrict__ b_loc,
                       int Na, int N) {
    int i = blockIdx.x * blockDim.x + threadIdx.x;
    if (i >= N) return;
    const int* p = (i < Na) ? (a_loc + (size_t)i * 3) : (b_loc + (size_t)(i - Na) * 3);
    int key = (p[0] << 16) | (p[1] << 8) | p[2];
    g_counts[key] = 1u;                                 // benign race: all write 1
}

// ---------------------------------------------------------------- block reduce (1024 keys/block)
__global__ void k_block_reduce() {
    __shared__ unsigned int s[256];
    int b = blockIdx.x, t = threadIdx.x;
    uint4 c = *reinterpret_cast<const uint4*>(&g_counts[b * 1024 + t * 4]);
    s[t] = c.x + c.y + c.z + c.w;
    __syncthreads();
    for (int off = 128; off > 0; off >>= 1) {
        if (t < off) s[t] += s[t + off];
        __syncthreads();
    }
    if (t == 0) g_blockSums[b] = s[0];
}

// ---------------------------------------------------------------- scan the 16384 block sums
__global__ void k_scan_blocks() {
    __shared__ unsigned int s[1024];
    int tid = threadIdx.x;
    int base = tid * 16;
    unsigned int local[16];
    unsigned int tot = 0;
#pragma unroll
    for (int k = 0; k < 16; ++k) { local[k] = g_blockSums[base + k]; tot += local[k]; }
    s[tid] = tot;
    __syncthreads();
    for (int off = 1; off < 1024; off <<= 1) {
        unsigned int v = (tid >= off) ? s[tid - off] : 0u;
        __syncthreads();
        s[tid] += v;
        __syncthreads();
    }
    unsigned int run = s[tid] - tot;                    // exclusive base for this thread
#pragma unroll
    for (int k = 0; k < 16; ++k) { unsigned int c = local[k]; g_blockSums[base + k] = run; run += c; }
}

// ---------------------------------------------------------------- rank + write sorted unique locations
__global__ void k_rank_write_loc(float* __restrict__ out_loc) {
    __shared__ unsigned int s[256];
    int b = blockIdx.x, t = threadIdx.x;
    int k0 = b * 1024 + t * 4;
    uint4 c = *reinterpret_cast<const uint4*>(&g_counts[k0]);
    unsigned int pres[4] = { c.x, c.y, c.z, c.w };
    unsigned int cnt = c.x + c.y + c.z + c.w;
    s[t] = cnt;
    __syncthreads();
    for (int off = 1; off < 256; off <<= 1) {
        unsigned int v = (t >= off) ? s[t - off] : 0u;
        __syncthreads();
        s[t] += v;
        __syncthreads();
    }
    unsigned int r = g_blockSums[b] + s[t] - cnt;       // exclusive rank for first key
#pragma unroll
    for (int k = 0; k < 4; ++k) {
        if (pres[k]) {
            int key = k0 + k;
            g_counts[key] = r;                          // overwrite presence with rank
            float* p = out_loc + (size_t)r * 3;
            p[0] = (float)(key >> 16);
            p[1] = (float)((key >> 8) & 255);
            p[2] = (float)(key & 255);
            ++r;
        }
    }
}

// ---------------------------------------------------------------- inverse indices + winner selection
__global__ void k_reverse(const int* __restrict__ a_loc, const int* __restrict__ b_loc,
                          int Na, int N) {
    int i = blockIdx.x * blockDim.x + threadIdx.x;
    if (i >= N) return;
    const int* p = (i < Na) ? (a_loc + (size_t)i * 3) : (b_loc + (size_t)(i - Na) * 3);
    int key = (p[0] << 16) | (p[1] << 8) | p[2];
    unsigned int r = g_counts[key];                     // rank of this row's location
    if (i < Na) atomicMax(&g_winner_a[r], i);           // last (max) row index wins,
    else        atomicMax(&g_winner_b[r], i - Na);      // matching XLA CPU scatter order
}

// ---------------------------------------------------------------- gather features
__global__ void k_gather(const float* __restrict__ a_feat, const float* __restrict__ b_feat,
                         float* __restrict__ out_feat, int N) {
    int idx = blockIdx.x * blockDim.x + threadIdx.x;    // N*32 threads, float4 each
    if (idx >= N * 32) return;
    int u  = idx >> 5;
    int c4 = (idx & 31) * 4;
    float4 v = make_float4(0.f, 0.f, 0.f, 0.f);
    if (c4 < 64) {
        int w = g_winner_a[u];
        if (w >= 0) v = *reinterpret_cast<const float4*>(a_feat + (size_t)w * 64 + c4);
    } else {
        int w = g_winner_b[u];
        if (w >= 0) v = *reinterpret_cast<const float4*>(b_feat + (size_t)w * 64 + (c4 - 64));
    }
    *reinterpret_cast<float4*>(out_feat + (size_t)u * 128 + c4) = v;
}

// ---------------------------------------------------------------- launch
extern "C" void kernel_launch(void* const* d_in, const int* in_sizes, int n_in,
                              void* d_out, int out_size, void* d_ws, size_t ws_size,
                              hipStream_t stream) {
    const int*   a_loc  = (const int*)  d_in[0];
    const float* a_feat = (const float*)d_in[1];
    const int*   b_loc  = (const int*)  d_in[2];
    const float* b_feat = (const float*)d_in[3];

    const int Na = in_sizes[0] / 3;
    const int Nb = in_sizes[2] / 3;
    const int N  = Na + Nb;                 // 400000

    float* out_loc  = (float*)d_out;        // N*3 floats (unique_locations, -1 padded)
    float* out_feat = out_loc + (size_t)N * 3;  // N*128 floats

    const int T = 256;

    k_zero_counts<<<NKEYS / 4 / T, T, 0, stream>>>();
    k_init<<<(N * 3 + T - 1) / T, T, 0, stream>>>(out_loc, N);
    k_mark<<<(N + T - 1) / T, T, 0, stream>>>(a_loc, b_loc, Na, N);
    k_block_reduce<<<NBLK, T, 0, stream>>>();
    k_scan_blocks<<<1, 1024, 0, stream>>>();
    k_rank_write_loc<<<NBLK, T, 0, stream>>>(out_loc);
    k_reverse<<<(N + T - 1) / T, T, 0, stream>>>(a_loc, b_loc, Na, N);
    k_gather<<<(N * 32 + T - 1) / T, T, 0, stream>>>(a_feat, b_feat, out_feat, N);
}

// Round 2
// 153.616 us; speedup vs baseline: 1.1911x; 1.1911x over previous
//
#include <hip/hip_runtime.h>
#include <hip/hip_bf16.h>

// Problem constants (fixed by setup_inputs): Na=Nb=200000, Da=Db=64, S=256.
#define NKEYS   (1 << 24)          // 256^3 possible locations
#define NW      (NKEYS / 32)       // 524288 32-bit presence words (2 MB)
#define WPT     4                  // words per thread in reduce/prefix passes (uint4)
#define TPB     256
#define WPB     (TPB * WPT)        // 1024 words per block
#define NBLK2   (NW / WPB)         // 512 blocks
#define MAXN    400000             // Na + Nb

// Device-global scratch. Re-initialized every call (deterministic).
__device__ unsigned int g_bits[NW];        // presence bitmask per key
__device__ unsigned int g_wordPrefix[NW];  // exclusive rank base per 32-key word
__device__ unsigned int g_blockSums[NBLK2];
__device__ int          g_winner_a[MAXN];  // per-unique-slot winning a-row (max index)
__device__ int          g_winner_b[MAXN];  // per-unique-slot winning b-row (max index)

// ---------------------------------------------------------------- fused init
__global__ void k_init(float* out_loc, int N) {
    int i = blockIdx.x * blockDim.x + threadIdx.x;          // ceil(3N) threads
    if (i < NW / 4) reinterpret_cast<uint4*>(g_bits)[i] = make_uint4(0u, 0u, 0u, 0u);
    if (i < N) { g_winner_a[i] = -1; g_winner_b[i] = -1; }
    if (i < N * 3) out_loc[i] = -1.0f;                      // fill_value=-1 padding rows
}

// ---------------------------------------------------------------- mark presence bits
__global__ void k_mark(const int* __restrict__ a_loc, const int* __restrict__ b_loc,
                       int Na, int N) {
    int i = blockIdx.x * blockDim.x + threadIdx.x;
    if (i >= N) return;
    const int* p = (i < Na) ? (a_loc + (size_t)i * 3) : (b_loc + (size_t)(i - Na) * 3);
    int key = (p[0] << 16) | (p[1] << 8) | p[2];
    atomicOr(&g_bits[key >> 5], 1u << (key & 31));
}

// ---------------------------------------------------------------- per-block popcount reduce
__global__ void k_reduce() {
    __shared__ unsigned int s[TPB];
    int b = blockIdx.x, t = threadIdx.x;
    uint4 w = reinterpret_cast<const uint4*>(g_bits)[b * TPB + t];
    s[t] = __popc(w.x) + __popc(w.y) + __popc(w.z) + __popc(w.w);
    __syncthreads();
    for (int off = TPB / 2; off > 0; off >>= 1) {
        if (t < off) s[t] += s[t + off];
        __syncthreads();
    }
    if (t == 0) g_blockSums[b] = s[0];
}

// ---------------------------------------------------------------- single-block scan of 512 block sums
__global__ void k_scan() {
    __shared__ unsigned int s[NBLK2];
    int t = threadIdx.x;                                    // 512 threads
    unsigned int v = g_blockSums[t];
    s[t] = v;
    __syncthreads();
    for (int off = 1; off < NBLK2; off <<= 1) {
        unsigned int u = (t >= off) ? s[t - off] : 0u;
        __syncthreads();
        s[t] += u;
        __syncthreads();
    }
    g_blockSums[t] = s[t] - v;                              // exclusive
}

// ---------------------------------------------------------------- word prefixes + sorted unique locations
__global__ void k_prefix_loc(float* __restrict__ out_loc) {
    __shared__ unsigned int s[TPB];
    int b = blockIdx.x, t = threadIdx.x;
    int w0 = (b * TPB + t) * WPT;                           // first word index for this thread
    uint4 wv = reinterpret_cast<const uint4*>(g_bits)[b * TPB + t];
    unsigned int wlocal[WPT] = { wv.x, wv.y, wv.z, wv.w };
    unsigned int cnt = __popc(wv.x) + __popc(wv.y) + __popc(wv.z) + __popc(wv.w);
    s[t] = cnt;
    __syncthreads();
    for (int off = 1; off < TPB; off <<= 1) {
        unsigned int u = (t >= off) ? s[t - off] : 0u;
        __syncthreads();
        s[t] += u;
        __syncthreads();
    }
    unsigned int r = g_blockSums[b] + s[t] - cnt;           // exclusive rank base
#pragma unroll
    for (int j = 0; j < WPT; ++j) {
        unsigned int bits = wlocal[j];
        g_wordPrefix[w0 + j] = r;
        while (bits) {
            int bit = __ffs(bits) - 1;
            bits &= bits - 1;
            int key = ((w0 + j) << 5) | bit;
            float* p = out_loc + (size_t)r * 3;
            p[0] = (float)(key >> 16);
            p[1] = (float)((key >> 8) & 255);
            p[2] = (float)(key & 255);
            ++r;
        }
    }
}

// ---------------------------------------------------------------- inverse indices + winner selection
__global__ void k_reverse(const int* __restrict__ a_loc, const int* __restrict__ b_loc,
                          int Na, int N) {
    int i = blockIdx.x * blockDim.x + threadIdx.x;
    if (i >= N) return;
    const int* p = (i < Na) ? (a_loc + (size_t)i * 3) : (b_loc + (size_t)(i - Na) * 3);
    int key = (p[0] << 16) | (p[1] << 8) | p[2];
    unsigned int word = g_bits[key >> 5];
    unsigned int r = g_wordPrefix[key >> 5] + __popc(word & ((1u << (key & 31)) - 1u));
    if (i < Na) atomicMax(&g_winner_a[r], i);               // last (max) row index wins,
    else        atomicMax(&g_winner_b[r], i - Na);          // matching XLA CPU scatter order
}

// ---------------------------------------------------------------- gather features
__global__ void k_gather(const float* __restrict__ a_feat, const float* __restrict__ b_feat,
                         float* __restrict__ out_feat, int N) {
    int idx = blockIdx.x * blockDim.x + threadIdx.x;        // N*32 threads, float4 each
    if (idx >= N * 32) return;
    int u  = idx >> 5;
    int c4 = (idx & 31) * 4;
    float4 v = make_float4(0.f, 0.f, 0.f, 0.f);
    if (c4 < 64) {
        int w = g_winner_a[u];
        if (w >= 0) v = *reinterpret_cast<const float4*>(a_feat + (size_t)w * 64 + c4);
    } else {
        int w = g_winner_b[u];
        if (w >= 0) v = *reinterpret_cast<const float4*>(b_feat + (size_t)w * 64 + (c4 - 64));
    }
    *reinterpret_cast<float4*>(out_feat + (size_t)u * 128 + c4) = v;
}

// ---------------------------------------------------------------- launch
extern "C" void kernel_launch(void* const* d_in, const int* in_sizes, int n_in,
                              void* d_out, int out_size, void* d_ws, size_t ws_size,
                              hipStream_t stream) {
    const int*   a_loc  = (const int*)  d_in[0];
    const float* a_feat = (const float*)d_in[1];
    const int*   b_loc  = (const int*)  d_in[2];
    const float* b_feat = (const float*)d_in[3];

    const int Na = in_sizes[0] / 3;
    const int Nb = in_sizes[2] / 3;
    const int N  = Na + Nb;                      // 400000

    float* out_loc  = (float*)d_out;             // N*3 floats (unique_locations, -1 padded)
    float* out_feat = out_loc + (size_t)N * 3;   // N*128 floats

    k_init<<<(N * 3 + TPB - 1) / TPB, TPB, 0, stream>>>(out_loc, N);
    k_mark<<<(N + TPB - 1) / TPB, TPB, 0, stream>>>(a_loc, b_loc, Na, N);
    k_reduce<<<NBLK2, TPB, 0, stream>>>();
    k_scan<<<1, NBLK2, 0, stream>>>();
    k_prefix_loc<<<NBLK2, TPB, 0, stream>>>(out_loc);
    k_reverse<<<(N + TPB - 1) / TPB, TPB, 0, stream>>>(a_loc, b_loc, Na, N);
    k_gather<<<(N * 32 + TPB - 1) / TPB, TPB, 0, stream>>>(a_feat, b_feat, out_feat, N);
}